// Round 1
// baseline (424.458 us; speedup 1.0000x reference)
//
#include <hip/hip_runtime.h>
#include <hip/hip_bf16.h>
#include <stdint.h>

// Re-Attention: x@Wqkv -> qk^T softmax -> cross-head mix -> LN(head axis) -> @v -> proj
// B=8 N=1024 H=8 D=64 DIM=512

#define NB 8
#define NSEQ 1024
#define NH 8
#define HD 64
#define DIMC 512
#define TNC 1536

typedef __attribute__((ext_vector_type(8))) short bf16x8;
typedef __attribute__((ext_vector_type(4))) float f32x4;
typedef __attribute__((ext_vector_type(8))) unsigned short u16x8;

__device__ __forceinline__ unsigned short f2bf(float f) {
    union { float f; uint32_t u; } v; v.f = f;
    uint32_t u = v.u;
    return (unsigned short)((u + 0x7fffu + ((u >> 16) & 1u)) >> 16);
}
__device__ __forceinline__ float bf2f(unsigned short s) {
    union { uint32_t u; float f; } v; v.u = ((uint32_t)s) << 16;
    return v.f;
}

#define MFMA(a, b, c) __builtin_amdgcn_mfma_f32_16x16x32_bf16((a), (b), (c), 0, 0, 0)

// ---------- fp32 -> bf16 bulk convert (8 elems/thread) ----------
__global__ void k_conv(const float* __restrict__ in, unsigned short* __restrict__ out, int n8) {
    int t = blockIdx.x * blockDim.x + threadIdx.x;
    if (t >= n8) return;
    const float4* p = reinterpret_cast<const float4*>(in) + (size_t)t * 2;
    float4 a = p[0], b = p[1];
    u16x8 o;
    o[0] = f2bf(a.x); o[1] = f2bf(a.y); o[2] = f2bf(a.z); o[3] = f2bf(a.w);
    o[4] = f2bf(b.x); o[5] = f2bf(b.y); o[6] = f2bf(b.z); o[7] = f2bf(b.w);
    *(reinterpret_cast<u16x8*>(out) + t) = o;
}

// ---------- fp32 [R][C] -> bf16 [C][R] transpose-convert ----------
__global__ __launch_bounds__(256) void k_tconv(const float* __restrict__ in,
                                               unsigned short* __restrict__ out, int R, int C) {
    __shared__ float tile[64][65];
    int ct = C >> 6;
    int bx = blockIdx.x % ct;   // col tile of input
    int by = blockIdx.x / ct;   // row tile of input
    int r0 = by * 64, c0 = bx * 64;
    int tx = threadIdx.x & 63, ty = threadIdx.x >> 6;
#pragma unroll
    for (int rr = 0; rr < 16; rr++) {
        int row = ty + rr * 4;
        tile[row][tx] = in[(size_t)(r0 + row) * C + c0 + tx];
    }
    __syncthreads();
#pragma unroll
    for (int rr = 0; rr < 16; rr++) {
        int row = ty + rr * 4;  // row within output c-tile
        out[(size_t)(c0 + row) * R + r0 + tx] = f2bf(tile[tx][row]);
    }
}

// ---------- QKV GEMM: xb[8192][512] @ wbT -> q(scaled)/k/v bf16 [b][h][n][d] ----------
__global__ __launch_bounds__(256) void k_qkv(const unsigned short* __restrict__ A,
                                             const unsigned short* __restrict__ BT,
                                             unsigned short* __restrict__ q,
                                             unsigned short* __restrict__ k,
                                             unsigned short* __restrict__ v) {
    int blk = blockIdx.x;
    int mt = blk / (TNC / 64), nt = blk % (TNC / 64);
    int m0 = mt * 64, c0 = nt * 64;
    int lane = threadIdx.x & 63, w = threadIdx.x >> 6;
    int lr = lane & 15, lb = lane >> 4;
    f32x4 acc[4] = {};
    int arow = m0 + 16 * w + lr;
    for (int ks = 0; ks < DIMC; ks += 32) {
        bf16x8 af = *reinterpret_cast<const bf16x8*>(A + (size_t)arow * DIMC + ks + 8 * lb);
#pragma unroll
        for (int t = 0; t < 4; t++) {
            bf16x8 bfg = *reinterpret_cast<const bf16x8*>(BT + (size_t)(c0 + 16 * t + lr) * DIMC + ks + 8 * lb);
            acc[t] = MFMA(af, bfg, acc[t]);
        }
    }
#pragma unroll
    for (int t = 0; t < 4; t++) {
        int c = c0 + 16 * t + lr;
        int which = c >> 9, rem = c & 511, h = rem >> 6, d = rem & 63;
        unsigned short* dst = which == 0 ? q : (which == 1 ? k : v);
        float sc = which == 0 ? 0.125f : 1.0f;   // q pre-scaled by D^-0.5
#pragma unroll
        for (int r = 0; r < 4; r++) {
            int m = m0 + 16 * w + 4 * lb + r;
            int b = m >> 10, n = m & 1023;
            dst[(((size_t)(b * 8 + h) * 1024) + n) * 64 + d] = f2bf(acc[t][r] * sc);
        }
    }
}

// ---------- v [bh][n][d] -> vT [bh][d][n] ----------
__global__ __launch_bounds__(256) void k_vtrans(const unsigned short* __restrict__ v,
                                                unsigned short* __restrict__ vT) {
    __shared__ unsigned short tile[64][72];
    int bh = blockIdx.x >> 4;
    int n0 = (blockIdx.x & 15) * 64;
    int t = threadIdx.x;
    int nl = t >> 2, c4 = t & 3;
    const u16x8* src = reinterpret_cast<const u16x8*>(v + ((size_t)bh * 1024 + n0 + nl) * 64 + c4 * 16);
    u16x8 x0 = src[0], x1 = src[1];
    *reinterpret_cast<u16x8*>(&tile[nl][c4 * 16]) = x0;
    *reinterpret_cast<u16x8*>(&tile[nl][c4 * 16 + 8]) = x1;
    __syncthreads();
    int dl = t >> 2, n4 = t & 3;
#pragma unroll
    for (int c = 0; c < 2; c++) {
        u16x8 o;
#pragma unroll
        for (int i = 0; i < 8; i++) o[i] = tile[n4 * 16 + 8 * c + i][dl];
        *reinterpret_cast<u16x8*>(vT + ((size_t)bh * 64 + dl) * 1024 + n0 + n4 * 16 + 8 * c) = o;
    }
}

// ---------- dots = q k^T (scale pre-applied) + row softmax -> attn bf16 ----------
__global__ __launch_bounds__(256) void k_attn(const unsigned short* __restrict__ q,
                                              const unsigned short* __restrict__ kk,
                                              unsigned short* __restrict__ attn) {
    int it = blockIdx.x & 63;   // i-tile (16 rows)
    int bh = blockIdx.x >> 6;
    int i0 = it * 16;
    int lane = threadIdx.x & 63, w = threadIdx.x >> 6;
    int lr = lane & 15, lb = lane >> 4;
    const unsigned short* qp = q + (size_t)bh * 1024 * 64;
    const unsigned short* kp = kk + (size_t)bh * 1024 * 64;
    f32x4 acc[16] = {};
    bf16x8 a0 = *reinterpret_cast<const bf16x8*>(qp + (size_t)(i0 + lr) * 64 + 0 + 8 * lb);
    bf16x8 a1 = *reinterpret_cast<const bf16x8*>(qp + (size_t)(i0 + lr) * 64 + 32 + 8 * lb);
#pragma unroll
    for (int t = 0; t < 16; t++) {
        int j0 = w * 256 + t * 16;
        bf16x8 b0 = *reinterpret_cast<const bf16x8*>(kp + (size_t)(j0 + lr) * 64 + 0 + 8 * lb);
        acc[t] = MFMA(a0, b0, acc[t]);
        bf16x8 b1 = *reinterpret_cast<const bf16x8*>(kp + (size_t)(j0 + lr) * 64 + 32 + 8 * lb);
        acc[t] = MFMA(a1, b1, acc[t]);
    }
    // softmax over full row (4 waves x 256 cols each)
    __shared__ float red[4][16];
    float mx[4], sm[4];
#pragma unroll
    for (int r = 0; r < 4; r++) {
        float m = acc[0][r];
#pragma unroll
        for (int t = 1; t < 16; t++) m = fmaxf(m, acc[t][r]);
        for (int off = 1; off < 16; off <<= 1) m = fmaxf(m, __shfl_xor(m, off));
        mx[r] = m;
    }
    if (lr == 0) {
#pragma unroll
        for (int r = 0; r < 4; r++) red[w][4 * lb + r] = mx[r];
    }
    __syncthreads();
#pragma unroll
    for (int r = 0; r < 4; r++) {
        int row = 4 * lb + r;
        mx[r] = fmaxf(fmaxf(red[0][row], red[1][row]), fmaxf(red[2][row], red[3][row]));
    }
    __syncthreads();
#pragma unroll
    for (int r = 0; r < 4; r++) {
        float s = 0.f;
#pragma unroll
        for (int t = 0; t < 16; t++) {
            float p = __expf(acc[t][r] - mx[r]);
            acc[t][r] = p;
            s += p;
        }
        for (int off = 1; off < 16; off <<= 1) s += __shfl_xor(s, off);
        sm[r] = s;
    }
    if (lr == 0) {
#pragma unroll
        for (int r = 0; r < 4; r++) red[w][4 * lb + r] = sm[r];
    }
    __syncthreads();
#pragma unroll
    for (int r = 0; r < 4; r++) {
        int row = 4 * lb + r;
        sm[r] = 1.0f / (red[0][row] + red[1][row] + red[2][row] + red[3][row]);
    }
    unsigned short* ap = attn + (size_t)bh * 1024 * 1024;
#pragma unroll
    for (int t = 0; t < 16; t++) {
#pragma unroll
        for (int r = 0; r < 4; r++) {
            ap[(size_t)(i0 + 4 * lb + r) * 1024 + w * 256 + t * 16 + lr] = f2bf(acc[t][r] * sm[r]);
        }
    }
}

// ---------- cross-head mix + LayerNorm over head axis, in place ----------
__global__ __launch_bounds__(256) void k_mixln(unsigned short* __restrict__ attn,
                                               const float* __restrict__ W,
                                               const float* __restrict__ gamma,
                                               const float* __restrict__ beta) {
    int t = blockIdx.x * 256 + threadIdx.x;     // (b, i, j/8): 8*1024*128 threads
    int j0 = (t & 127) * 8;
    int i = (t >> 7) & 1023;
    int b = t >> 17;
    float w[64];
#pragma unroll
    for (int x = 0; x < 64; x++) w[x] = W[x];
    float g[8], bt[8];
#pragma unroll
    for (int x = 0; x < 8; x++) { g[x] = gamma[x]; bt[x] = beta[x]; }
    float a[8][8];
    size_t base = ((size_t)(b * 8) * 1024 + i) * 1024 + j0;
#pragma unroll
    for (int h = 0; h < 8; h++) {
        u16x8 xv = *reinterpret_cast<const u16x8*>(attn + base + (size_t)h * 1024 * 1024);
#pragma unroll
        for (int jj = 0; jj < 8; jj++) a[h][jj] = bf2f(xv[jj]);
    }
    u16x8 o[8];
#pragma unroll
    for (int jj = 0; jj < 8; jj++) {
        float mg[8]; float s = 0.f;
#pragma unroll
        for (int gg = 0; gg < 8; gg++) {
            float m = 0.f;
#pragma unroll
            for (int h = 0; h < 8; h++) m += a[h][jj] * w[h * 8 + gg];
            mg[gg] = m; s += m;
        }
        float mean = s * 0.125f;
        float ss = 0.f;
#pragma unroll
        for (int gg = 0; gg < 8; gg++) { float d2 = mg[gg] - mean; ss += d2 * d2; }
        float rs = rsqrtf(ss * 0.125f + 1e-5f);
#pragma unroll
        for (int gg = 0; gg < 8; gg++) o[gg][jj] = f2bf((mg[gg] - mean) * rs * g[gg] + bt[gg]);
    }
#pragma unroll
    for (int gg = 0; gg < 8; gg++)
        *reinterpret_cast<u16x8*>(attn + base + (size_t)gg * 1024 * 1024) = o[gg];
}

// ---------- PV: attn[bh][1024][1024] @ v -> outh bf16 [b][n][h*64+d] ----------
__global__ __launch_bounds__(256) void k_pv(const unsigned short* __restrict__ attn,
                                            const unsigned short* __restrict__ vT,
                                            unsigned short* __restrict__ outh) {
    int it = blockIdx.x & 15;
    int bh = blockIdx.x >> 4;
    int i0 = it * 64;
    int lane = threadIdx.x & 63, w = threadIdx.x >> 6;
    int lr = lane & 15, lb = lane >> 4;
    const unsigned short* ap = attn + (size_t)bh * 1024 * 1024;
    const unsigned short* vp = vT + (size_t)bh * 64 * 1024;
    f32x4 acc[4] = {};
    int arow = i0 + 16 * w + lr;
    for (int kk2 = 0; kk2 < 1024; kk2 += 32) {
        bf16x8 af = *reinterpret_cast<const bf16x8*>(ap + (size_t)arow * 1024 + kk2 + 8 * lb);
#pragma unroll
        for (int t = 0; t < 4; t++) {
            bf16x8 bfg = *reinterpret_cast<const bf16x8*>(vp + (size_t)(t * 16 + lr) * 1024 + kk2 + 8 * lb);
            acc[t] = MFMA(af, bfg, acc[t]);
        }
    }
    int b = bh >> 3, h = bh & 7;
#pragma unroll
    for (int t = 0; t < 4; t++) {
        int d = t * 16 + lr;
#pragma unroll
        for (int r = 0; r < 4; r++) {
            int i = i0 + 16 * w + 4 * lb + r;
            outh[((size_t)(b * 1024 + i)) * 512 + h * 64 + d] = f2bf(acc[t][r]);
        }
    }
}

// ---------- out = outh @ w_out + b_out (fp32 out) ----------
__global__ __launch_bounds__(256) void k_proj(const unsigned short* __restrict__ A,
                                              const unsigned short* __restrict__ BT,
                                              const float* __restrict__ bias,
                                              float* __restrict__ out) {
    int blk = blockIdx.x;
    int mt = blk >> 3, nt = blk & 7;
    int m0 = mt * 64, c0 = nt * 64;
    int lane = threadIdx.x & 63, w = threadIdx.x >> 6;
    int lr = lane & 15, lb = lane >> 4;
    f32x4 acc[4] = {};
    int arow = m0 + 16 * w + lr;
    for (int ks = 0; ks < DIMC; ks += 32) {
        bf16x8 af = *reinterpret_cast<const bf16x8*>(A + (size_t)arow * DIMC + ks + 8 * lb);
#pragma unroll
        for (int t = 0; t < 4; t++) {
            bf16x8 bfg = *reinterpret_cast<const bf16x8*>(BT + (size_t)(c0 + 16 * t + lr) * DIMC + ks + 8 * lb);
            acc[t] = MFMA(af, bfg, acc[t]);
        }
    }
#pragma unroll
    for (int t = 0; t < 4; t++) {
        int c = c0 + 16 * t + lr;
        float bs = bias[c];
#pragma unroll
        for (int r = 0; r < 4; r++) {
            int m = m0 + 16 * w + 4 * lb + r;
            out[(size_t)m * 512 + c] = acc[t][r] + bs;
        }
    }
}

extern "C" void kernel_launch(void* const* d_in, const int* in_sizes, int n_in,
                              void* d_out, int out_size, void* d_ws, size_t ws_size,
                              hipStream_t stream) {
    (void)in_sizes; (void)n_in; (void)out_size; (void)ws_size;
    const float* x      = (const float*)d_in[0];
    const float* w_qkv  = (const float*)d_in[1];
    const float* W      = (const float*)d_in[2];
    const float* gamma  = (const float*)d_in[3];
    const float* beta   = (const float*)d_in[4];
    const float* w_out  = (const float*)d_in[5];
    const float* b_out  = (const float*)d_in[6];
    float* out = (float*)d_out;

    char* ws = (char*)d_ws;
    unsigned short* xb    = (unsigned short*)(ws + 0);           //  8 MB  [8192][512]
    unsigned short* wbT   = (unsigned short*)(ws + 8388608);     //  1.5MB [1536][512]
    unsigned short* w_oT  = (unsigned short*)(ws + 9961472);     //  0.5MB [512][512]
    unsigned short* q     = (unsigned short*)(ws + 10485760);    //  8 MB  [bh][n][d]
    unsigned short* k     = (unsigned short*)(ws + 18874368);    //  8 MB
    unsigned short* v     = (unsigned short*)(ws + 27262976);    //  8 MB
    unsigned short* vT    = (unsigned short*)(ws + 35651584);    //  8 MB  [bh][d][n]
    unsigned short* outh  = (unsigned short*)(ws + 44040192);    //  8 MB  [8192][512]
    unsigned short* attn  = (unsigned short*)(ws + 52428800);    // 128 MB [bh][i][j]

    k_conv<<<2048, 256, 0, stream>>>(x, xb, 8192 * 512 / 8);
    k_tconv<<<(512 / 64) * (1536 / 64), 256, 0, stream>>>(w_qkv, wbT, 512, 1536);
    k_tconv<<<(512 / 64) * (512 / 64), 256, 0, stream>>>(w_out, w_oT, 512, 512);
    k_qkv<<<(8192 / 64) * (1536 / 64), 256, 0, stream>>>(xb, wbT, q, k, v);
    k_vtrans<<<64 * 16, 256, 0, stream>>>(v, vT);
    k_attn<<<64 * 64, 256, 0, stream>>>(q, k, attn);
    k_mixln<<<4096, 256, 0, stream>>>(attn, W, gamma, beta);
    k_pv<<<64 * 16, 256, 0, stream>>>(attn, vT, outh);
    k_proj<<<(8192 / 64) * (512 / 64), 256, 0, stream>>>(outh, w_oT, b_out, out);
}

// Round 2
// 324.685 us; speedup vs baseline: 1.3073x; 1.3073x over previous
//
#include <hip/hip_runtime.h>
#include <hip/hip_bf16.h>
#include <stdint.h>

// Re-Attention: x@Wqkv -> qk^T softmax -> cross-head mix -> LN(head axis) -> @v -> proj
// B=8 N=1024 H=8 D=64 DIM=512
// Round 2: LDS-tiled QKV/proj GEMMs (m97 structure); attn matrix never materialized:
// pass1 computes row (max, 1/sum); pass2 recomputes QK^T, mixes+LNs across heads in LDS,
// and PV-accumulates per head. Saves ~512MB of HBM traffic vs round 1.

#define DIMC 512

typedef __attribute__((ext_vector_type(8))) short bf16x8;
typedef __attribute__((ext_vector_type(4))) float f32x4;
typedef __attribute__((ext_vector_type(8))) unsigned short u16x8;

__device__ __forceinline__ unsigned short f2bf(float f) {
    union { float f; uint32_t u; } v; v.f = f;
    uint32_t u = v.u;
    return (unsigned short)((u + 0x7fffu + ((u >> 16) & 1u)) >> 16);
}
__device__ __forceinline__ float bf2f(unsigned short s) {
    union { uint32_t u; float f; } v; v.u = ((uint32_t)s) << 16;
    return v.f;
}

#define MFMA(a, b, c) __builtin_amdgcn_mfma_f32_16x16x32_bf16((a), (b), (c), 0, 0, 0)

#define GLOAD16(gptr, lptr)                                                        \
    __builtin_amdgcn_global_load_lds((const __attribute__((address_space(1))) void*)(gptr), \
                                     (__attribute__((address_space(3))) void*)(lptr), 16, 0, 0)

// ---------- fp32 -> bf16 bulk convert (8 elems/thread) ----------
__global__ void k_conv(const float* __restrict__ in, unsigned short* __restrict__ out, int n8) {
    int t = blockIdx.x * blockDim.x + threadIdx.x;
    if (t >= n8) return;
    const float4* p = reinterpret_cast<const float4*>(in) + (size_t)t * 2;
    float4 a = p[0], b = p[1];
    u16x8 o;
    o[0] = f2bf(a.x); o[1] = f2bf(a.y); o[2] = f2bf(a.z); o[3] = f2bf(a.w);
    o[4] = f2bf(b.x); o[5] = f2bf(b.y); o[6] = f2bf(b.z); o[7] = f2bf(b.w);
    *(reinterpret_cast<u16x8*>(out) + t) = o;
}

// ---------- fp32 [R][C] -> bf16 [C][R] transpose-convert ----------
__global__ __launch_bounds__(256) void k_tconv(const float* __restrict__ in,
                                               unsigned short* __restrict__ out, int R, int C) {
    __shared__ float tile[64][65];
    int ct = C >> 6;
    int bx = blockIdx.x % ct;
    int by = blockIdx.x / ct;
    int r0 = by * 64, c0 = bx * 64;
    int tx = threadIdx.x & 63, ty = threadIdx.x >> 6;
#pragma unroll
    for (int rr = 0; rr < 16; rr++) {
        int row = ty + rr * 4;
        tile[row][tx] = in[(size_t)(r0 + row) * C + c0 + tx];
    }
    __syncthreads();
#pragma unroll
    for (int rr = 0; rr < 16; rr++) {
        int row = ty + rr * 4;
        out[(size_t)(c0 + row) * R + r0 + tx] = f2bf(tile[tx][row]);
    }
}

// ---------- QKV GEMM, 128x128 LDS tile: xb[8192][512] @ wbT^T -> q(scaled)/k/v ----------
__global__ __launch_bounds__(256) void k_qkv(const unsigned short* __restrict__ A,
                                             const unsigned short* __restrict__ BT,
                                             unsigned short* __restrict__ q,
                                             unsigned short* __restrict__ kk,
                                             unsigned short* __restrict__ vv) {
    __shared__ unsigned short Al[128 * 32];
    __shared__ unsigned short Bl[128 * 32];
    int mt = blockIdx.x / 12, nt = blockIdx.x % 12;
    int m0 = mt * 128, c0 = nt * 128;
    int tid = threadIdx.x, lane = tid & 63, w = tid >> 6;
    int wr = w >> 1, wc = w & 1;
    int lr = lane & 15, lb = lane >> 4;
    f32x4 acc[4][4] = {};
    const unsigned short* gA = A + (size_t)(m0 + 32 * w + (lane >> 2)) * DIMC + (lane & 3) * 8;
    const unsigned short* gB = BT + (size_t)(c0 + 32 * w + (lane >> 2)) * DIMC + (lane & 3) * 8;
    char* lA = (char*)Al + w * 2048;
    char* lB = (char*)Bl + w * 2048;
    for (int k0 = 0; k0 < DIMC; k0 += 32) {
        __syncthreads();
        GLOAD16(gA + k0, lA);
        GLOAD16(gA + k0 + 16 * DIMC, lA + 1024);
        GLOAD16(gB + k0, lB);
        GLOAD16(gB + k0 + 16 * DIMC, lB + 1024);
        __syncthreads();
        bf16x8 af[4], bfr[4];
#pragma unroll
        for (int mi = 0; mi < 4; mi++)
            af[mi] = *reinterpret_cast<const bf16x8*>(&Al[(64 * wr + 16 * mi + lr) * 32 + 8 * lb]);
#pragma unroll
        for (int ni = 0; ni < 4; ni++)
            bfr[ni] = *reinterpret_cast<const bf16x8*>(&Bl[(64 * wc + 16 * ni + lr) * 32 + 8 * lb]);
#pragma unroll
        for (int mi = 0; mi < 4; mi++)
#pragma unroll
            for (int ni = 0; ni < 4; ni++)
                acc[mi][ni] = MFMA(af[mi], bfr[ni], acc[mi][ni]);
    }
#pragma unroll
    for (int ni = 0; ni < 4; ni++) {
        int c = c0 + 64 * wc + 16 * ni + lr;
        int which = c >> 9, rem = c & 511, h = rem >> 6, d = rem & 63;
        unsigned short* dst = which == 0 ? q : (which == 1 ? kk : vv);
        float sc = which == 0 ? 0.125f : 1.0f;  // q pre-scaled by D^-0.5
#pragma unroll
        for (int mi = 0; mi < 4; mi++) {
#pragma unroll
            for (int r = 0; r < 4; r++) {
                int m = m0 + 64 * wr + 16 * mi + 4 * lb + r;
                int b = m >> 10, n = m & 1023;
                dst[(((size_t)(b * 8 + h) * 1024) + n) * 64 + d] = f2bf(acc[mi][ni][r] * sc);
            }
        }
    }
}

// ---------- v [bh][n][d] -> vT [bh][d][n] ----------
__global__ __launch_bounds__(256) void k_vtrans(const unsigned short* __restrict__ v,
                                                unsigned short* __restrict__ vT) {
    __shared__ unsigned short tile[64][72];
    int bh = blockIdx.x >> 4;
    int n0 = (blockIdx.x & 15) * 64;
    int t = threadIdx.x;
    int nl = t >> 2, c4 = t & 3;
    const u16x8* src = reinterpret_cast<const u16x8*>(v + ((size_t)bh * 1024 + n0 + nl) * 64 + c4 * 16);
    u16x8 x0 = src[0], x1 = src[1];
    *reinterpret_cast<u16x8*>(&tile[nl][c4 * 16]) = x0;
    *reinterpret_cast<u16x8*>(&tile[nl][c4 * 16 + 8]) = x1;
    __syncthreads();
    int dl = t >> 2, n4 = t & 3;
#pragma unroll
    for (int c = 0; c < 2; c++) {
        u16x8 o;
#pragma unroll
        for (int i = 0; i < 8; i++) o[i] = tile[n4 * 16 + 8 * c + i][dl];
        *reinterpret_cast<u16x8*>(vT + ((size_t)bh * 64 + dl) * 1024 + n0 + n4 * 16 + 8 * c) = o;
    }
}

// ---------- pass 1: row max + 1/rowsum of exp for softmax (no attn store) ----------
__global__ __launch_bounds__(256) void k_ml(const unsigned short* __restrict__ q,
                                            const unsigned short* __restrict__ kk,
                                            float* __restrict__ m_out,
                                            float* __restrict__ linv_out) {
    int it = blockIdx.x & 63;
    int bh = blockIdx.x >> 6;
    int i0 = it * 16;
    int lane = threadIdx.x & 63, w = threadIdx.x >> 6;
    int lr = lane & 15, lb = lane >> 4;
    const unsigned short* qp = q + (size_t)bh * 1024 * 64;
    const unsigned short* kp = kk + (size_t)bh * 1024 * 64;
    f32x4 acc[16] = {};
    bf16x8 a0 = *reinterpret_cast<const bf16x8*>(qp + (size_t)(i0 + lr) * 64 + 0 + 8 * lb);
    bf16x8 a1 = *reinterpret_cast<const bf16x8*>(qp + (size_t)(i0 + lr) * 64 + 32 + 8 * lb);
#pragma unroll
    for (int t = 0; t < 16; t++) {
        int j0 = w * 256 + t * 16;
        bf16x8 b0 = *reinterpret_cast<const bf16x8*>(kp + (size_t)(j0 + lr) * 64 + 0 + 8 * lb);
        acc[t] = MFMA(a0, b0, acc[t]);
        bf16x8 b1 = *reinterpret_cast<const bf16x8*>(kp + (size_t)(j0 + lr) * 64 + 32 + 8 * lb);
        acc[t] = MFMA(a1, b1, acc[t]);
    }
    __shared__ float red[4][16];
    float mx[4], sm[4];
#pragma unroll
    for (int r = 0; r < 4; r++) {
        float m = acc[0][r];
#pragma unroll
        for (int t = 1; t < 16; t++) m = fmaxf(m, acc[t][r]);
        for (int off = 1; off < 16; off <<= 1) m = fmaxf(m, __shfl_xor(m, off));
        mx[r] = m;
    }
    if (lr == 0) {
#pragma unroll
        for (int r = 0; r < 4; r++) red[w][4 * lb + r] = mx[r];
    }
    __syncthreads();
#pragma unroll
    for (int r = 0; r < 4; r++) {
        int row = 4 * lb + r;
        mx[r] = fmaxf(fmaxf(red[0][row], red[1][row]), fmaxf(red[2][row], red[3][row]));
    }
    __syncthreads();
#pragma unroll
    for (int r = 0; r < 4; r++) {
        float s = 0.f;
#pragma unroll
        for (int t = 0; t < 16; t++) s += __expf(acc[t][r] - mx[r]);
        for (int off = 1; off < 16; off <<= 1) s += __shfl_xor(s, off);
        sm[r] = s;
    }
    if (lr == 0) {
#pragma unroll
        for (int r = 0; r < 4; r++) red[w][4 * lb + r] = sm[r];
    }
    __syncthreads();
    if (w == 0 && lr == 0) {
#pragma unroll
        for (int r = 0; r < 4; r++) {
            int row = 4 * lb + r;
            float tot = red[0][row] + red[1][row] + red[2][row] + red[3][row];
            m_out[(size_t)bh * 1024 + i0 + row] = mx[r];
            linv_out[(size_t)bh * 1024 + i0 + row] = 1.0f / tot;
        }
    }
}

// ---------- pass 2: recompute QK^T, normalize, cross-head mix + LN, PV ----------
// block = (b, 16-row i-tile), 8 waves = 8 heads, j streamed in 64-wide tiles.
__global__ __launch_bounds__(512) void k_fused(const unsigned short* __restrict__ q,
                                               const unsigned short* __restrict__ kk,
                                               const unsigned short* __restrict__ vT,
                                               const float* __restrict__ m_arr,
                                               const float* __restrict__ l_arr,
                                               const float* __restrict__ W,
                                               const float* __restrict__ gamma,
                                               const float* __restrict__ beta,
                                               unsigned short* __restrict__ outh) {
    __shared__ float P[8][16 * 65];              // normalized attn, f32, pad 65
    __shared__ unsigned short PM[8][16 * 72];    // mixed+LN attn, bf16, pad 72 (16B-aligned rows)
    int b = blockIdx.x >> 6, it = blockIdx.x & 63, i0 = it * 16;
    int tid = threadIdx.x, h = tid >> 6, lane = tid & 63;
    int lr = lane & 15, lb = lane >> 4;
    int bh = b * 8 + h;
    const unsigned short* qp = q + (size_t)bh * 65536;
    const unsigned short* kp = kk + (size_t)bh * 65536;
    const unsigned short* vp = vT + (size_t)bh * 65536;
    bf16x8 aq0 = *reinterpret_cast<const bf16x8*>(qp + (size_t)(i0 + lr) * 64 + 8 * lb);
    bf16x8 aq1 = *reinterpret_cast<const bf16x8*>(qp + (size_t)(i0 + lr) * 64 + 32 + 8 * lb);
    float mr[4], li[4];
#pragma unroll
    for (int r = 0; r < 4; r++) {
        mr[r] = m_arr[(size_t)bh * 1024 + i0 + 4 * lb + r];
        li[r] = l_arr[(size_t)bh * 1024 + i0 + 4 * lb + r];
    }
    // uniform params -> expect SGPRs
    float wv[64];
#pragma unroll
    for (int x = 0; x < 64; x++) wv[x] = W[x];
    float gv[8], bv[8];
#pragma unroll
    for (int x = 0; x < 8; x++) { gv[x] = gamma[x]; bv[x] = beta[x]; }
    f32x4 accO[4] = {};
    int mj = tid & 63;                  // mix-phase j
    int mi0 = tid >> 6;                 // mix-phase i base
    for (int jt = 0; jt < 16; jt++) {
        int j0 = jt * 64;
        // QK^T for this head (q pre-scaled)
        f32x4 s[4] = {};
#pragma unroll
        for (int f = 0; f < 4; f++) {
            bf16x8 bk0 = *reinterpret_cast<const bf16x8*>(kp + (size_t)(j0 + 16 * f + lr) * 64 + 8 * lb);
            s[f] = MFMA(aq0, bk0, s[f]);
            bf16x8 bk1 = *reinterpret_cast<const bf16x8*>(kp + (size_t)(j0 + 16 * f + lr) * 64 + 32 + 8 * lb);
            s[f] = MFMA(aq1, bk1, s[f]);
        }
        // normalize + publish to LDS
#pragma unroll
        for (int f = 0; f < 4; f++)
#pragma unroll
            for (int r = 0; r < 4; r++)
                P[h][(4 * lb + r) * 65 + 16 * f + lr] = __expf(s[f][r] - mr[r]) * li[r];
        __syncthreads();
        // cross-head mix + LN: each lane owns 2 (i,j) entries, computes all 8 outputs
#pragma unroll
        for (int e = 0; e < 2; e++) {
            int il = mi0 + 8 * e;
            float av[8];
#pragma unroll
            for (int hh = 0; hh < 8; hh++) av[hh] = P[hh][il * 65 + mj];
            float mg[8], sum = 0.f;
#pragma unroll
            for (int g = 0; g < 8; g++) {
                float m = 0.f;
#pragma unroll
                for (int hh = 0; hh < 8; hh++) m += av[hh] * wv[hh * 8 + g];
                mg[g] = m; sum += m;
            }
            float mean = sum * 0.125f;
            float ss = 0.f;
#pragma unroll
            for (int g = 0; g < 8; g++) { float d = mg[g] - mean; ss += d * d; }
            float rs = rsqrtf(ss * 0.125f + 1e-5f);
#pragma unroll
            for (int g = 0; g < 8; g++)
                PM[g][il * 72 + mj] = f2bf((mg[g] - mean) * rs * gv[g] + bv[g]);
        }
        __syncthreads();
        // PV for this head's mixed attn
#pragma unroll
        for (int kc = 0; kc < 2; kc++) {
            bf16x8 ap = *reinterpret_cast<const bf16x8*>(&PM[h][lr * 72 + 32 * kc + 8 * lb]);
#pragma unroll
            for (int df = 0; df < 4; df++) {
                bf16x8 bvv = *reinterpret_cast<const bf16x8*>(vp + (size_t)(16 * df + lr) * 1024 + j0 + 32 * kc + 8 * lb);
                accO[df] = MFMA(ap, bvv, accO[df]);
            }
        }
    }
#pragma unroll
    for (int df = 0; df < 4; df++) {
#pragma unroll
        for (int r = 0; r < 4; r++) {
            int i = i0 + 4 * lb + r;
            outh[((size_t)(b * 1024 + i)) * 512 + h * 64 + 16 * df + lr] = f2bf(accO[df][r]);
        }
    }
}

// ---------- out = outh @ w_out + b_out (fp32 out), 128x128 LDS tile ----------
__global__ __launch_bounds__(256) void k_proj(const unsigned short* __restrict__ A,
                                              const unsigned short* __restrict__ BT,
                                              const float* __restrict__ bias,
                                              float* __restrict__ out) {
    __shared__ unsigned short Al[128 * 32];
    __shared__ unsigned short Bl[128 * 32];
    int mt = blockIdx.x >> 2, nt = blockIdx.x & 3;
    int m0 = mt * 128, c0 = nt * 128;
    int tid = threadIdx.x, lane = tid & 63, w = tid >> 6;
    int wr = w >> 1, wc = w & 1;
    int lr = lane & 15, lb = lane >> 4;
    f32x4 acc[4][4] = {};
    const unsigned short* gA = A + (size_t)(m0 + 32 * w + (lane >> 2)) * DIMC + (lane & 3) * 8;
    const unsigned short* gB = BT + (size_t)(c0 + 32 * w + (lane >> 2)) * DIMC + (lane & 3) * 8;
    char* lA = (char*)Al + w * 2048;
    char* lB = (char*)Bl + w * 2048;
    for (int k0 = 0; k0 < DIMC; k0 += 32) {
        __syncthreads();
        GLOAD16(gA + k0, lA);
        GLOAD16(gA + k0 + 16 * DIMC, lA + 1024);
        GLOAD16(gB + k0, lB);
        GLOAD16(gB + k0 + 16 * DIMC, lB + 1024);
        __syncthreads();
        bf16x8 af[4], bfr[4];
#pragma unroll
        for (int mi = 0; mi < 4; mi++)
            af[mi] = *reinterpret_cast<const bf16x8*>(&Al[(64 * wr + 16 * mi + lr) * 32 + 8 * lb]);
#pragma unroll
        for (int ni = 0; ni < 4; ni++)
            bfr[ni] = *reinterpret_cast<const bf16x8*>(&Bl[(64 * wc + 16 * ni + lr) * 32 + 8 * lb]);
#pragma unroll
        for (int mi = 0; mi < 4; mi++)
#pragma unroll
            for (int ni = 0; ni < 4; ni++)
                acc[mi][ni] = MFMA(af[mi], bfr[ni], acc[mi][ni]);
    }
#pragma unroll
    for (int ni = 0; ni < 4; ni++) {
        int c = c0 + 64 * wc + 16 * ni + lr;
        float bs = bias[c];
#pragma unroll
        for (int mi = 0; mi < 4; mi++) {
#pragma unroll
            for (int r = 0; r < 4; r++) {
                int m = m0 + 64 * wr + 16 * mi + 4 * lb + r;
                out[(size_t)m * 512 + c] = acc[mi][ni][r] + bs;
            }
        }
    }
}

extern "C" void kernel_launch(void* const* d_in, const int* in_sizes, int n_in,
                              void* d_out, int out_size, void* d_ws, size_t ws_size,
                              hipStream_t stream) {
    (void)in_sizes; (void)n_in; (void)out_size; (void)ws_size;
    const float* x      = (const float*)d_in[0];
    const float* w_qkv  = (const float*)d_in[1];
    const float* W      = (const float*)d_in[2];
    const float* gamma  = (const float*)d_in[3];
    const float* beta   = (const float*)d_in[4];
    const float* w_out  = (const float*)d_in[5];
    const float* b_out  = (const float*)d_in[6];
    float* out = (float*)d_out;

    char* ws = (char*)d_ws;
    unsigned short* xb   = (unsigned short*)(ws + 0);           //  8 MB  [8192][512]
    unsigned short* wbT  = (unsigned short*)(ws + 8388608);     //  1.5MB [1536][512]
    unsigned short* w_oT = (unsigned short*)(ws + 9961472);     //  0.5MB [512][512]
    unsigned short* q    = (unsigned short*)(ws + 10485760);    //  8 MB  [bh][n][d]
    unsigned short* k    = (unsigned short*)(ws + 18874368);    //  8 MB
    unsigned short* v    = (unsigned short*)(ws + 27262976);    //  8 MB
    unsigned short* vT   = (unsigned short*)(ws + 35651584);    //  8 MB  [bh][d][n]
    unsigned short* outh = (unsigned short*)(ws + 44040192);    //  8 MB  [8192][512]
    float* m_arr         = (float*)(ws + 52428800);             // 256 KB [bh][n]
    float* l_arr         = (float*)(ws + 52690944);             // 256 KB [bh][n]

    k_conv<<<2048, 256, 0, stream>>>(x, xb, 8192 * 512 / 8);
    k_tconv<<<(512 / 64) * (1536 / 64), 256, 0, stream>>>(w_qkv, wbT, 512, 1536);
    k_tconv<<<(512 / 64) * (512 / 64), 256, 0, stream>>>(w_out, w_oT, 512, 512);
    k_qkv<<<(8192 / 128) * (1536 / 128), 256, 0, stream>>>(xb, wbT, q, k, v);
    k_vtrans<<<64 * 16, 256, 0, stream>>>(v, vT);
    k_ml<<<64 * 64, 256, 0, stream>>>(q, k, m_arr, l_arr);
    k_fused<<<8 * 64, 512, 0, stream>>>(q, k, vT, m_arr, l_arr, W, gamma, beta, outh);
    k_proj<<<(8192 / 128) * (512 / 128), 256, 0, stream>>>(outh, w_oT, b_out, out);
}

// Round 3
// 260.492 us; speedup vs baseline: 1.6294x; 1.2464x over previous
//
#include <hip/hip_runtime.h>
#include <hip/hip_bf16.h>
#include <stdint.h>

// Re-Attention: x@Wqkv -> qk^T softmax -> cross-head mix -> LN(head axis) -> @v -> proj
// B=8 N=1024 H=8 D=64 DIM=512
// Round 3: single-pass softmax (P materialized bf16, 128MB), XCD-swizzled grids for
// L2 residency of K/vT, mix+LN+PV fused kernel with global_load_lds staging and
// XOR-swizzled PM buffer. k_ml and QK^T recompute eliminated.

#define DIMC 512

typedef __attribute__((ext_vector_type(8))) short bf16x8;
typedef __attribute__((ext_vector_type(4))) float f32x4;
typedef __attribute__((ext_vector_type(8))) unsigned short u16x8;

__device__ __forceinline__ unsigned short f2bf(float f) {
    union { float f; uint32_t u; } v; v.f = f;
    uint32_t u = v.u;
    return (unsigned short)((u + 0x7fffu + ((u >> 16) & 1u)) >> 16);
}

#define MFMA(a, b, c) __builtin_amdgcn_mfma_f32_16x16x32_bf16((a), (b), (c), 0, 0, 0)

#define GLOAD16(gptr, lptr)                                                        \
    __builtin_amdgcn_global_load_lds((const __attribute__((address_space(1))) void*)(gptr), \
                                     (__attribute__((address_space(3))) void*)(lptr), 16, 0, 0)

// ---------- fp32 -> bf16 bulk convert (8 elems/thread) ----------
__global__ void k_conv(const float* __restrict__ in, unsigned short* __restrict__ out, int n8) {
    int t = blockIdx.x * blockDim.x + threadIdx.x;
    if (t >= n8) return;
    const float4* p = reinterpret_cast<const float4*>(in) + (size_t)t * 2;
    float4 a = p[0], b = p[1];
    u16x8 o;
    o[0] = f2bf(a.x); o[1] = f2bf(a.y); o[2] = f2bf(a.z); o[3] = f2bf(a.w);
    o[4] = f2bf(b.x); o[5] = f2bf(b.y); o[6] = f2bf(b.z); o[7] = f2bf(b.w);
    *(reinterpret_cast<u16x8*>(out) + t) = o;
}

// ---------- fp32 [R][C] -> bf16 [C][R] transpose-convert ----------
__global__ __launch_bounds__(256) void k_tconv(const float* __restrict__ in,
                                               unsigned short* __restrict__ out, int R, int C) {
    __shared__ float tile[64][65];
    int ct = C >> 6;
    int bx = blockIdx.x % ct;
    int by = blockIdx.x / ct;
    int r0 = by * 64, c0 = bx * 64;
    int tx = threadIdx.x & 63, ty = threadIdx.x >> 6;
#pragma unroll
    for (int rr = 0; rr < 16; rr++) {
        int row = ty + rr * 4;
        tile[row][tx] = in[(size_t)(r0 + row) * C + c0 + tx];
    }
    __syncthreads();
#pragma unroll
    for (int rr = 0; rr < 16; rr++) {
        int row = ty + rr * 4;
        out[(size_t)(c0 + row) * R + r0 + tx] = f2bf(tile[tx][row]);
    }
}

// ---------- QKV GEMM, 128x128 LDS tile: xb[8192][512] @ wbT^T -> q(scaled)/k/v ----------
__global__ __launch_bounds__(256) void k_qkv(const unsigned short* __restrict__ A,
                                             const unsigned short* __restrict__ BT,
                                             unsigned short* __restrict__ q,
                                             unsigned short* __restrict__ kk,
                                             unsigned short* __restrict__ vv) {
    __shared__ unsigned short Al[128 * 32];
    __shared__ unsigned short Bl[128 * 32];
    int mt = blockIdx.x / 12, nt = blockIdx.x % 12;
    int m0 = mt * 128, c0 = nt * 128;
    int tid = threadIdx.x, lane = tid & 63, w = tid >> 6;
    int wr = w >> 1, wc = w & 1;
    int lr = lane & 15, lb = lane >> 4;
    f32x4 acc[4][4] = {};
    const unsigned short* gA = A + (size_t)(m0 + 32 * w + (lane >> 2)) * DIMC + (lane & 3) * 8;
    const unsigned short* gB = BT + (size_t)(c0 + 32 * w + (lane >> 2)) * DIMC + (lane & 3) * 8;
    char* lA = (char*)Al + w * 2048;
    char* lB = (char*)Bl + w * 2048;
    for (int k0 = 0; k0 < DIMC; k0 += 32) {
        __syncthreads();
        GLOAD16(gA + k0, lA);
        GLOAD16(gA + k0 + 16 * DIMC, lA + 1024);
        GLOAD16(gB + k0, lB);
        GLOAD16(gB + k0 + 16 * DIMC, lB + 1024);
        __syncthreads();
        bf16x8 af[4], bfr[4];
#pragma unroll
        for (int mi = 0; mi < 4; mi++)
            af[mi] = *reinterpret_cast<const bf16x8*>(&Al[(64 * wr + 16 * mi + lr) * 32 + 8 * lb]);
#pragma unroll
        for (int ni = 0; ni < 4; ni++)
            bfr[ni] = *reinterpret_cast<const bf16x8*>(&Bl[(64 * wc + 16 * ni + lr) * 32 + 8 * lb]);
#pragma unroll
        for (int mi = 0; mi < 4; mi++)
#pragma unroll
            for (int ni = 0; ni < 4; ni++)
                acc[mi][ni] = MFMA(af[mi], bfr[ni], acc[mi][ni]);
    }
#pragma unroll
    for (int ni = 0; ni < 4; ni++) {
        int c = c0 + 64 * wc + 16 * ni + lr;
        int which = c >> 9, rem = c & 511, h = rem >> 6, d = rem & 63;
        unsigned short* dst = which == 0 ? q : (which == 1 ? kk : vv);
        float sc = which == 0 ? 0.125f : 1.0f;  // q pre-scaled by D^-0.5
#pragma unroll
        for (int mi = 0; mi < 4; mi++) {
#pragma unroll
            for (int r = 0; r < 4; r++) {
                int m = m0 + 64 * wr + 16 * mi + 4 * lb + r;
                int b = m >> 10, n = m & 1023;
                dst[(((size_t)(b * 8 + h) * 1024) + n) * 64 + d] = f2bf(acc[mi][ni][r] * sc);
            }
        }
    }
}

// ---------- v [bh][n][d] -> vT [bh][d][n] ----------
__global__ __launch_bounds__(256) void k_vtrans(const unsigned short* __restrict__ v,
                                                unsigned short* __restrict__ vT) {
    __shared__ unsigned short tile[64][72];
    int bh = blockIdx.x >> 4;
    int n0 = (blockIdx.x & 15) * 64;
    int t = threadIdx.x;
    int nl = t >> 2, c4 = t & 3;
    const u16x8* src = reinterpret_cast<const u16x8*>(v + ((size_t)bh * 1024 + n0 + nl) * 64 + c4 * 16);
    u16x8 x0 = src[0], x1 = src[1];
    *reinterpret_cast<u16x8*>(&tile[nl][c4 * 16]) = x0;
    *reinterpret_cast<u16x8*>(&tile[nl][c4 * 16 + 8]) = x1;
    __syncthreads();
    int dl = t >> 2, n4 = t & 3;
#pragma unroll
    for (int c = 0; c < 2; c++) {
        u16x8 o;
#pragma unroll
        for (int i = 0; i < 8; i++) o[i] = tile[n4 * 16 + 8 * c + i][dl];
        *reinterpret_cast<u16x8*>(vT + ((size_t)bh * 64 + dl) * 1024 + n0 + n4 * 16 + 8 * c) = o;
    }
}

// ---------- QK^T + full-row softmax -> P bf16 [bh][i][j] ----------
// block = (bh, 32 i-rows); 8 waves each own a 128-wide j strip; S held in regs.
// XCD swizzle: bh = blk&63 so all i-tiles of a bh share an XCD (K,Q L2-resident).
__global__ __launch_bounds__(512) void k_attn(const unsigned short* __restrict__ q,
                                              const unsigned short* __restrict__ kk,
                                              unsigned short* __restrict__ P) {
    __shared__ float redm[32][8];
    __shared__ float redl[32][8];
    int blk = blockIdx.x;
    int bh = blk & 63, it = blk >> 6;
    int i0 = it * 32;
    int tid = threadIdx.x, w = tid >> 6, lane = tid & 63;
    int lr = lane & 15, lb = lane >> 4;
    int j0 = w * 128;
    const unsigned short* qp = q + (size_t)bh * 65536;
    const unsigned short* kp = kk + (size_t)bh * 65536;
    bf16x8 aq[2][2];
#pragma unroll
    for (int mf = 0; mf < 2; mf++)
#pragma unroll
        for (int ks = 0; ks < 2; ks++)
            aq[mf][ks] = *reinterpret_cast<const bf16x8*>(qp + (size_t)(i0 + 16 * mf + lr) * 64 + 32 * ks + 8 * lb);
    f32x4 acc[2][8] = {};
#pragma unroll
    for (int nf = 0; nf < 8; nf++) {
#pragma unroll
        for (int ks = 0; ks < 2; ks++) {
            bf16x8 bk = *reinterpret_cast<const bf16x8*>(kp + (size_t)(j0 + 16 * nf + lr) * 64 + 32 * ks + 8 * lb);
            acc[0][nf] = MFMA(aq[0][ks], bk, acc[0][nf]);
            acc[1][nf] = MFMA(aq[1][ks], bk, acc[1][nf]);
        }
    }
    float mfin[2][4];
#pragma unroll
    for (int mf = 0; mf < 2; mf++)
#pragma unroll
        for (int r = 0; r < 4; r++) {
            float m = acc[mf][0][r];
#pragma unroll
            for (int nf = 1; nf < 8; nf++) m = fmaxf(m, acc[mf][nf][r]);
            m = fmaxf(m, __shfl_xor(m, 1)); m = fmaxf(m, __shfl_xor(m, 2));
            m = fmaxf(m, __shfl_xor(m, 4)); m = fmaxf(m, __shfl_xor(m, 8));
            mfin[mf][r] = m;
        }
    if (lr == 0) {
#pragma unroll
        for (int mf = 0; mf < 2; mf++)
#pragma unroll
            for (int r = 0; r < 4; r++) redm[16 * mf + 4 * lb + r][w] = mfin[mf][r];
    }
    __syncthreads();
#pragma unroll
    for (int mf = 0; mf < 2; mf++)
#pragma unroll
        for (int r = 0; r < 4; r++) {
            int row = 16 * mf + 4 * lb + r;
            float m = redm[row][0];
#pragma unroll
            for (int ww = 1; ww < 8; ww++) m = fmaxf(m, redm[row][ww]);
            mfin[mf][r] = m;
        }
    float lfin[2][4];
#pragma unroll
    for (int mf = 0; mf < 2; mf++)
#pragma unroll
        for (int r = 0; r < 4; r++) {
            float s = 0.f;
#pragma unroll
            for (int nf = 0; nf < 8; nf++) {
                float e = __expf(acc[mf][nf][r] - mfin[mf][r]);
                acc[mf][nf][r] = e;
                s += e;
            }
            s += __shfl_xor(s, 1); s += __shfl_xor(s, 2);
            s += __shfl_xor(s, 4); s += __shfl_xor(s, 8);
            lfin[mf][r] = s;
        }
    if (lr == 0) {
#pragma unroll
        for (int mf = 0; mf < 2; mf++)
#pragma unroll
            for (int r = 0; r < 4; r++) redl[16 * mf + 4 * lb + r][w] = lfin[mf][r];
    }
    __syncthreads();
#pragma unroll
    for (int mf = 0; mf < 2; mf++)
#pragma unroll
        for (int r = 0; r < 4; r++) {
            int row = 16 * mf + 4 * lb + r;
            float s = 0.f;
#pragma unroll
            for (int ww = 0; ww < 8; ww++) s += redl[row][ww];
            lfin[mf][r] = 1.0f / s;
        }
    unsigned short* pp = P + (size_t)bh * 1048576;
#pragma unroll
    for (int mf = 0; mf < 2; mf++)
#pragma unroll
        for (int nf = 0; nf < 8; nf++)
#pragma unroll
            for (int r = 0; r < 4; r++)
                pp[(size_t)(i0 + 16 * mf + 4 * lb + r) * 1024 + j0 + 16 * nf + lr] =
                    f2bf(acc[mf][nf][r] * lfin[mf][r]);
}

// ---------- mix + LN + PV fused: read P (all 8 heads), write outh ----------
// block = (b, 16 i-rows); 8 waves = 8 heads; j in 16 tiles of 64.
// ph1: global_load_lds P tile -> Pex (linear). ph2: mix+LN -> PM (XOR-swizzled).
// ph3: PV MFMA from PM + vT, overlapped with ph1 of next tile. 2 barriers/tile.
__global__ __launch_bounds__(512) void k_mixpv(const unsigned short* __restrict__ P,
                                               const unsigned short* __restrict__ vT,
                                               const float* __restrict__ Wm,
                                               const float* __restrict__ gamma,
                                               const float* __restrict__ beta,
                                               unsigned short* __restrict__ outh) {
    __shared__ unsigned short Pex[8 * 1024];   // [h][16][64] linear
    __shared__ unsigned short PMl[8 * 1024];   // [g][16][64], byte-addr ^ ((i&7)<<4)
    int blk = blockIdx.x;
    int b = blk & 7, it = blk >> 3;
    int i0 = it * 16;
    int tid = threadIdx.x, w = tid >> 6, lane = tid & 63;
    int lr = lane & 15, lb = lane >> 4;
    float wv[64];
#pragma unroll
    for (int x2 = 0; x2 < 64; x2++) wv[x2] = Wm[x2];
    float cv[8];  // mean folding: c_h = sum_g W[h][g] / 8
#pragma unroll
    for (int h = 0; h < 8; h++) {
        float s = 0.f;
#pragma unroll
        for (int g = 0; g < 8; g++) s += wv[h * 8 + g];
        cv[h] = s * 0.125f;
    }
    float gv[8], bvv[8];
#pragma unroll
    for (int x2 = 0; x2 < 8; x2++) { gv[x2] = gamma[x2]; bvv[x2] = beta[x2]; }
    const unsigned short* pbase = P + (size_t)(b * 8 + w) * 1048576 + (size_t)i0 * 1024;
    const unsigned short* vp = vT + (size_t)(b * 8 + w) * 65536;
    int ii = tid >> 5;          // ph2 row 0..15
    int jj = (tid & 31) * 2;    // ph2 col pair
    f32x4 accO[4] = {};

    auto PH1 = [&](int jt) {
        int j0 = jt * 64;
#pragma unroll
        for (int c = 0; c < 2; c++) {
            int o = c * 512 + lane * 8;            // u16 offset within 16x64 tile
            GLOAD16(pbase + (size_t)(o >> 6) * 1024 + j0 + (o & 63),
                    (char*)Pex + w * 2048 + c * 1024);
        }
    };
    auto PH2 = [&]() {
        float alo[8], ahi[8];
#pragma unroll
        for (int h = 0; h < 8; h++) {
            uint32_t pv = *reinterpret_cast<const uint32_t*>(Pex + h * 1024 + ii * 64 + jj);
            alo[h] = __uint_as_float(pv << 16);
            ahi[h] = __uint_as_float(pv & 0xffff0000u);
        }
        float mgl[8], mgh[8];
        float meanl = 0.f, meanh = 0.f;
#pragma unroll
        for (int g = 0; g < 8; g++) {
            float sl = 0.f, sh = 0.f;
#pragma unroll
            for (int h = 0; h < 8; h++) { sl += alo[h] * wv[h * 8 + g]; sh += ahi[h] * wv[h * 8 + g]; }
            mgl[g] = sl; mgh[g] = sh;
        }
#pragma unroll
        for (int h = 0; h < 8; h++) { meanl += alo[h] * cv[h]; meanh += ahi[h] * cv[h]; }
        float vl = 0.f, vh = 0.f;
#pragma unroll
        for (int g = 0; g < 8; g++) {
            float dl = mgl[g] - meanl, dh = mgh[g] - meanh;
            vl += dl * dl; vh += dh * dh;
        }
        float rl = rsqrtf(vl * 0.125f + 1e-5f), rh = rsqrtf(vh * 0.125f + 1e-5f);
#pragma unroll
        for (int g = 0; g < 8; g++) {
            unsigned short ol = f2bf((mgl[g] - meanl) * rl * gv[g] + bvv[g]);
            unsigned short oh = f2bf((mgh[g] - meanh) * rh * gv[g] + bvv[g]);
            uint32_t pk = (uint32_t)ol | ((uint32_t)oh << 16);
            int byteoff = (g * 2048 + ii * 128 + jj * 2) ^ ((ii & 7) << 4);
            *reinterpret_cast<uint32_t*>((char*)PMl + byteoff) = pk;
        }
    };
    auto PH3 = [&](int jt) {
        int j0 = jt * 64;
        bf16x8 Af[2];
#pragma unroll
        for (int kc = 0; kc < 2; kc++) {
            int byteoff = (w * 2048 + lr * 128 + kc * 64 + lb * 16) ^ ((lr & 7) << 4);
            Af[kc] = *reinterpret_cast<const bf16x8*>((const char*)PMl + byteoff);
        }
#pragma unroll
        for (int kc = 0; kc < 2; kc++)
#pragma unroll
            for (int df = 0; df < 4; df++) {
                bf16x8 bv8 = *reinterpret_cast<const bf16x8*>(vp + (size_t)(16 * df + lr) * 1024 + j0 + 32 * kc + 8 * lb);
                accO[df] = MFMA(Af[kc], bv8, accO[df]);
            }
    };

    PH1(0);
    __syncthreads();
    PH2();
    __syncthreads();
    for (int jt = 0; jt < 16; jt++) {
        if (jt < 15) PH1(jt + 1);
        PH3(jt);
        __syncthreads();
        if (jt < 15) PH2();
        __syncthreads();
    }
    int bi = b * 1024 + i0;
#pragma unroll
    for (int df = 0; df < 4; df++)
#pragma unroll
        for (int r = 0; r < 4; r++)
            outh[(size_t)(bi + 4 * lb + r) * 512 + w * 64 + 16 * df + lr] = f2bf(accO[df][r]);
}

// ---------- out = outh @ w_out + b_out (fp32 out), 128x128 LDS tile ----------
__global__ __launch_bounds__(256) void k_proj(const unsigned short* __restrict__ A,
                                              const unsigned short* __restrict__ BT,
                                              const float* __restrict__ bias,
                                              float* __restrict__ out) {
    __shared__ unsigned short Al[128 * 32];
    __shared__ unsigned short Bl[128 * 32];
    int mt = blockIdx.x >> 2, nt = blockIdx.x & 3;
    int m0 = mt * 128, c0 = nt * 128;
    int tid = threadIdx.x, lane = tid & 63, w = tid >> 6;
    int wr = w >> 1, wc = w & 1;
    int lr = lane & 15, lb = lane >> 4;
    f32x4 acc[4][4] = {};
    const unsigned short* gA = A + (size_t)(m0 + 32 * w + (lane >> 2)) * DIMC + (lane & 3) * 8;
    const unsigned short* gB = BT + (size_t)(c0 + 32 * w + (lane >> 2)) * DIMC + (lane & 3) * 8;
    char* lA = (char*)Al + w * 2048;
    char* lB = (char*)Bl + w * 2048;
    for (int k0 = 0; k0 < DIMC; k0 += 32) {
        __syncthreads();
        GLOAD16(gA + k0, lA);
        GLOAD16(gA + k0 + 16 * DIMC, lA + 1024);
        GLOAD16(gB + k0, lB);
        GLOAD16(gB + k0 + 16 * DIMC, lB + 1024);
        __syncthreads();
        bf16x8 af[4], bfr[4];
#pragma unroll
        for (int mi = 0; mi < 4; mi++)
            af[mi] = *reinterpret_cast<const bf16x8*>(&Al[(64 * wr + 16 * mi + lr) * 32 + 8 * lb]);
#pragma unroll
        for (int ni = 0; ni < 4; ni++)
            bfr[ni] = *reinterpret_cast<const bf16x8*>(&Bl[(64 * wc + 16 * ni + lr) * 32 + 8 * lb]);
#pragma unroll
        for (int mi = 0; mi < 4; mi++)
#pragma unroll
            for (int ni = 0; ni < 4; ni++)
                acc[mi][ni] = MFMA(af[mi], bfr[ni], acc[mi][ni]);
    }
#pragma unroll
    for (int ni = 0; ni < 4; ni++) {
        int c = c0 + 64 * wc + 16 * ni + lr;
        float bs = bias[c];
#pragma unroll
        for (int mi = 0; mi < 4; mi++) {
#pragma unroll
            for (int r = 0; r < 4; r++) {
                int m = m0 + 64 * wr + 16 * mi + 4 * lb + r;
                out[(size_t)m * 512 + c] = acc[mi][ni][r] + bs;
            }
        }
    }
}

extern "C" void kernel_launch(void* const* d_in, const int* in_sizes, int n_in,
                              void* d_out, int out_size, void* d_ws, size_t ws_size,
                              hipStream_t stream) {
    (void)in_sizes; (void)n_in; (void)out_size; (void)ws_size;
    const float* x      = (const float*)d_in[0];
    const float* w_qkv  = (const float*)d_in[1];
    const float* W      = (const float*)d_in[2];
    const float* gamma  = (const float*)d_in[3];
    const float* beta   = (const float*)d_in[4];
    const float* w_out  = (const float*)d_in[5];
    const float* b_out  = (const float*)d_in[6];
    float* out = (float*)d_out;

    char* ws = (char*)d_ws;
    unsigned short* xb   = (unsigned short*)(ws + 0);           //  8 MB  [8192][512]
    unsigned short* wbT  = (unsigned short*)(ws + 8388608);     //  1.5MB [1536][512]
    unsigned short* w_oT = (unsigned short*)(ws + 9961472);     //  0.5MB [512][512]
    unsigned short* q    = (unsigned short*)(ws + 10485760);    //  8 MB  [bh][n][d]
    unsigned short* k    = (unsigned short*)(ws + 18874368);    //  8 MB
    unsigned short* v    = (unsigned short*)(ws + 27262976);    //  8 MB
    unsigned short* vT   = (unsigned short*)(ws + 35651584);    //  8 MB  [bh][d][n]
    unsigned short* outh = (unsigned short*)(ws + 44040192);    //  8 MB  [8192][512]
    unsigned short* P    = (unsigned short*)(ws + 52428800);    // 128 MB [bh][i][j]

    k_conv<<<2048, 256, 0, stream>>>(x, xb, 8192 * 512 / 8);
    k_tconv<<<(512 / 64) * (1536 / 64), 256, 0, stream>>>(w_qkv, wbT, 512, 1536);
    k_tconv<<<(512 / 64) * (512 / 64), 256, 0, stream>>>(w_out, w_oT, 512, 512);
    k_qkv<<<(8192 / 128) * (1536 / 128), 256, 0, stream>>>(xb, wbT, q, k, v);
    k_vtrans<<<64 * 16, 256, 0, stream>>>(v, vT);
    k_attn<<<64 * 32, 512, 0, stream>>>(q, k, P);
    k_mixpv<<<8 * 64, 512, 0, stream>>>(P, vT, W, gamma, beta, outh);
    k_proj<<<(8192 / 128) * (512 / 128), 256, 0, stream>>>(outh, w_oT, b_out, out);
}